// Round 1
// baseline (1101.444 us; speedup 1.0000x reference)
//
#include <hip/hip_runtime.h>

// GAT attention aggregator, fully fused single pass over neigh_vecs.
// N=50000, K=32, D_IN=D_OUT=128. bf16 MFMA (16x16x32), fp32 accumulate.

constexpr int D   = 128;
constexpr int KN  = 32;   // neighbors per node
constexpr int NPB = 8;    // nodes per block
constexpr int XS_ROWS = 48;   // 32 neigh + 1 self + 15 zero pad rows (M=48 MFMA tile)
constexpr int LDP = 136;      // padded leading dim (bf16 elems): +8 keeps 16B align, breaks bank conflicts

typedef __bf16 bf16;
typedef __attribute__((ext_vector_type(8))) __bf16 bf16x8;
typedef __attribute__((ext_vector_type(4))) __bf16 bf16x4;
typedef __attribute__((ext_vector_type(4))) float  f32x4;

// Pre-transpose feat_weights [k][n] fp32 -> Wt_g [n][k] bf16 (one-shot, 64 KB read)
__global__ void prep_wt_kernel(const float* __restrict__ W, bf16* __restrict__ Wt) {
  int i = blockIdx.x * 256 + threadIdx.x;
  if (i < D * D) {
    int n = i >> 7, k = i & 127;
    Wt[i] = (bf16)W[(k << 7) + n];
  }
}

__global__ __launch_bounds__(256, 3)
void gat_kernel(const float* __restrict__ selfv,
                const float* __restrict__ neighv,
                const float* __restrict__ Wfp,
                const bf16*  __restrict__ Wt_g,
                const float* __restrict__ attn,
                const float* __restrict__ biasp,
                float* __restrict__ out,
                int nnodes, int use_ws)
{
  __shared__ __align__(16) bf16 Wt[D][LDP];       // 34816 B, W^T (n-major, k contiguous)
  __shared__ __align__(16) bf16 Xs[XS_ROWS][LDP]; // 13056 B, per-node A tile
  __shared__ float lp[4][KN];                     // per-wave logit partials
  __shared__ float slp[4];                        // per-wave self-logit partials
  __shared__ float coefs[KN];

  const int tid  = threadIdx.x;
  const int w    = tid >> 6;
  const int lane = tid & 63;
  const int q    = lane >> 4;
  const int l15  = lane & 15;
  const int colbase = w << 5;   // each wave owns 32 output cols

  // ---- stage W^T into LDS (bf16) ----
  if (use_ws) {
    const ulonglong2* src = (const ulonglong2*)Wt_g;  // 16B chunks
    for (int i = tid; i < (D * D) / 8; i += 256) {
      int r = i >> 4, c8 = i & 15;
      *(ulonglong2*)&Wt[r][c8 << 3] = src[i];
    }
  } else {
    for (int i = tid; i < D * D; i += 256) {
      int n = i >> 7, k = i & 127;
      Wt[n][k] = (bf16)Wfp[(k << 7) + n];
    }
  }
  // zero the M-padding rows 33..47 (read by mt=2 MFMA tile)
  for (int i = tid; i < (XS_ROWS - 33) * LDP; i += 256)
    (&Xs[33][0])[i] = (bf16)0.0f;

  // per-thread constants (L1/L2 cached, tiny)
  const float a0 = attn[colbase + l15];
  const float a1 = attn[colbase + 16 + l15];
  const float b0 = biasp[colbase + l15];
  const float b1 = biasp[colbase + 16 + l15];

  __syncthreads();

  // ---- hoist B fragments (W^T) — constant across all nodes ----
  // B[k = q*8+j][n = l15]: 8 contiguous k from Wt row n
  bf16x8 Bf[2][4];
  #pragma unroll
  for (int nt = 0; nt < 2; ++nt)
    #pragma unroll
    for (int ks = 0; ks < 4; ++ks)
      Bf[nt][ks] = *(const bf16x8*)&Wt[colbase + nt * 16 + l15][ks * 32 + q * 8];

  const int node0 = blockIdx.x * NPB;
  const float4* neigh4 = (const float4*)neighv;
  const float4* self4  = (const float4*)selfv;

  float4 pn[4];   // prefetch regs: 32 rows * 128 f32 = 1024 float4 / 256 thr
  float4 ps;      // self row: 32 float4, threads 0..31

  auto load_node = [&](int node) {
    size_t base = (size_t)node * (KN * D / 4);
    #pragma unroll
    for (int i = 0; i < 4; ++i) pn[i] = neigh4[base + tid + i * 256];
    if (tid < 32) ps = self4[(size_t)node * (D / 4) + tid];
  };
  auto store_node_lds = [&]() {
    #pragma unroll
    for (int i = 0; i < 4; ++i) {
      int idx4 = tid + i * 256;
      int row = idx4 >> 5, c4 = idx4 & 31;
      bf16x4 v = { (bf16)pn[i].x, (bf16)pn[i].y, (bf16)pn[i].z, (bf16)pn[i].w };
      *(bf16x4*)&Xs[row][c4 << 2] = v;
    }
    if (tid < 32) {
      bf16x4 v = { (bf16)ps.x, (bf16)ps.y, (bf16)ps.z, (bf16)ps.w };
      *(bf16x4*)&Xs[32][tid << 2] = v;
    }
  };

  if (node0 < nnodes) { load_node(node0); store_node_lds(); }

  for (int ni = 0; ni < NPB; ++ni) {
    const int node = node0 + ni;
    const bool valid = node < nnodes;           // block-uniform
    __syncthreads();                            // Xs staged & visible

    const bool pvalid = (ni + 1 < NPB) && (node + 1 < nnodes);
    if (pvalid) load_node(node + 1);            // issue early; lands during compute

    f32x4 acc[3][2];
    if (valid) {
      #pragma unroll
      for (int mt = 0; mt < 3; ++mt)
        #pragma unroll
        for (int nt = 0; nt < 2; ++nt)
          acc[mt][nt] = (f32x4){0.f, 0.f, 0.f, 0.f};

      // H[48][128] = Xs @ W  (rows 0..31 neigh, 32 self, 33..47 zero)
      #pragma unroll
      for (int ks = 0; ks < 4; ++ks) {
        bf16x8 Af[3];
        #pragma unroll
        for (int mt = 0; mt < 3; ++mt)   // A[m = l15][k = q*8+j]
          Af[mt] = *(const bf16x8*)&Xs[mt * 16 + l15][ks * 32 + q * 8];
        #pragma unroll
        for (int mt = 0; mt < 3; ++mt)
          #pragma unroll
          for (int nt = 0; nt < 2; ++nt)
            acc[mt][nt] = __builtin_amdgcn_mfma_f32_16x16x32_bf16(
                Af[mt], Bf[nt][ks], acc[mt][nt], 0, 0, 0);
      }

      // neigh logit partials: C/D layout col=l15, row=q*4+reg
      #pragma unroll
      for (int mt = 0; mt < 2; ++mt) {
        #pragma unroll
        for (int r = 0; r < 4; ++r) {
          float v = acc[mt][0][r] * a0 + acc[mt][1][r] * a1;
          v += __shfl_xor(v, 1); v += __shfl_xor(v, 2);
          v += __shfl_xor(v, 4); v += __shfl_xor(v, 8);
          if (l15 == 0) lp[w][mt * 16 + (q << 2) + r] = v;
        }
      }
      { // self logit partial: h_self = H row 32 = acc[2][*][0] at q==0 (lanes 0..15)
        float v = acc[2][0][0] * a0 + acc[2][1][0] * a1;
        v += __shfl_xor(v, 1); v += __shfl_xor(v, 2);
        v += __shfl_xor(v, 4); v += __shfl_xor(v, 8);
        if (lane == 0) slp[w] = v;
      }
    }
    __syncthreads();

    // wave 0: leaky_relu + softmax over K=32
    if (valid && w == 0) {
      float sl = slp[0] + slp[1] + slp[2] + slp[3];
      float t = 0.f;
      if (lane < 32) t = lp[0][lane] + lp[1][lane] + lp[2][lane] + lp[3][lane] + sl;
      t = t > 0.f ? t : 0.2f * t;
      float m = t;
      #pragma unroll
      for (int msk = 16; msk >= 1; msk >>= 1) m = fmaxf(m, __shfl_xor(m, msk, 32));
      float e = __expf(t - m);
      float s = e;
      #pragma unroll
      for (int msk = 16; msk >= 1; msk >>= 1) s += __shfl_xor(s, msk, 32);
      if (lane < 32) coefs[lane] = e / s;
    }
    __syncthreads();

    // aggregation straight from acc fragments + epilogue
    if (valid) {
      #pragma unroll
      for (int nt = 0; nt < 2; ++nt) {
        float p = 0.f;
        #pragma unroll
        for (int mt = 0; mt < 2; ++mt)
          #pragma unroll
          for (int r = 0; r < 4; ++r)
            p += coefs[mt * 16 + (q << 2) + r] * acc[mt][nt][r];
        p += __shfl_xor(p, 16);   // combine the 4 q-groups (rows)
        p += __shfl_xor(p, 32);
        float ov = acc[2][nt][0] + p + (nt ? b1 : b0);  // h_self + h_neighs + bias
        ov = fmaxf(ov, 0.f);
        if (lane < 16) out[(size_t)node * D + colbase + nt * 16 + lane] = ov;
      }
    }
    __syncthreads();              // all Xs reads + coefs reads done
    if (pvalid) store_node_lds(); // write prefetched node (waits on vmcnt here)
  }
}

extern "C" void kernel_launch(void* const* d_in, const int* in_sizes, int n_in,
                              void* d_out, int out_size, void* d_ws, size_t ws_size,
                              hipStream_t stream) {
  const float* selfv  = (const float*)d_in[0];
  const float* neighv = (const float*)d_in[1];
  const float* W      = (const float*)d_in[2];
  const float* attn   = (const float*)d_in[3];
  const float* biasp  = (const float*)d_in[4];
  float* out = (float*)d_out;
  const int nnodes = in_sizes[0] / D;

  const int use_ws = (ws_size >= (size_t)(D * D * sizeof(bf16))) ? 1 : 0;
  bf16* Wt_g = (bf16*)d_ws;
  if (use_ws)
    prep_wt_kernel<<<(D * D + 255) / 256, 256, 0, stream>>>(W, Wt_g);

  const int nblocks = (nnodes + NPB - 1) / NPB;
  gat_kernel<<<nblocks, 256, 0, stream>>>(selfv, neighv, W, Wt_g, attn, biasp,
                                          out, nnodes, use_ws);
}

// Round 2
// 1077.569 us; speedup vs baseline: 1.0222x; 1.0222x over previous
//
#include <hip/hip_runtime.h>

// GAT attention aggregator — wave-per-node, zero main-loop barriers.
// N=50000, K=32, D_IN=D_OUT=128. bf16 MFMA 16x16x32, fp32 accum.
// Each 64-lane wave owns one node at a time: stages its 33-row X tile
// (32 neigh + self) into a private LDS region, computes H = X @ W for all
// 128 cols (3mt x 8nt x 4ks MFMAs), then does logits/softmax/aggregation
// entirely in-register via shuffles. Waves never synchronize after startup.

constexpr int D   = 128;
constexpr int KN  = 32;
constexpr int NPW = 4;            // nodes per wave
constexpr int LDP = 136;          // padded leading dim (bf16 elems) — breaks bank conflicts
constexpr int XR  = 33;           // rows per wave region (32 neigh + 1 self)
constexpr int XROWS_TOTAL = 4 * XR + 15;  // +15: mt=2 tile overreads rows 33..47 (garbage, ignored)

typedef __bf16 bf16;
typedef __attribute__((ext_vector_type(8))) __bf16 bf16x8;
typedef __attribute__((ext_vector_type(4))) __bf16 bf16x4;
typedef __attribute__((ext_vector_type(4))) float  f32x4;

// One-shot: feat_weights [k][n] fp32 -> W^T [n][k] bf16 in workspace
__global__ void prep_wt_kernel(const float* __restrict__ W, bf16* __restrict__ Wt) {
  int i = blockIdx.x * 256 + threadIdx.x;
  if (i < D * D) {
    int n = i >> 7, k = i & 127;
    Wt[i] = (bf16)W[(k << 7) + n];
  }
}

__global__ __launch_bounds__(256, 2)
void gat_kernel(const float* __restrict__ selfv,
                const float* __restrict__ neighv,
                const float* __restrict__ Wfp,
                const bf16*  __restrict__ Wt_g,
                const float* __restrict__ attn,
                const float* __restrict__ biasp,
                float* __restrict__ out,
                int nnodes, int use_ws)
{
  __shared__ __align__(16) bf16 Wt[D][LDP];            // 34816 B, W^T (n-major, k contiguous)
  __shared__ __align__(16) bf16 Xs[XROWS_TOTAL][LDP];  // 39984 B, 4 per-wave regions

  const int tid  = threadIdx.x;
  const int w    = tid >> 6;
  const int lane = tid & 63;
  const int q    = lane >> 4;
  const int l15  = lane & 15;

  // ---- stage W^T into LDS (cooperative, once) ----
  if (use_ws) {
    const ulonglong2* src = (const ulonglong2*)Wt_g;
    for (int i = tid; i < (D * D) / 8; i += 256) {
      int r = i >> 4, c8 = i & 15;
      *(ulonglong2*)&Wt[r][c8 << 3] = src[i];
    }
  } else {
    for (int i = tid; i < D * D; i += 256) {
      int n = i >> 7, k = i & 127;
      Wt[n][k] = (bf16)Wfp[(k << 7) + n];
    }
  }

  // per-lane constants: attn & bias for cols nt*16+l15
  float av[8], bv[8];
  #pragma unroll
  for (int nt = 0; nt < 8; ++nt) {
    av[nt] = attn[nt * 16 + l15];
    bv[nt] = biasp[nt * 16 + l15];
  }

  __syncthreads();  // W^T visible; last block-wide barrier

  bf16* Xw = &Xs[w * XR][0];
  const float4* neigh4 = (const float4*)neighv;
  const float4* self4  = (const float4*)selfv;
  const int gw = blockIdx.x * 4 + w;

  for (int i = 0; i < NPW; ++i) {
    const int node = gw * NPW + i;
    if (node >= nnodes) break;   // wave-uniform

    // ---- stage node i into this wave's LDS region (rows 0..31 neigh, 32 self) ----
    {
      const size_t nb = (size_t)node * (KN * D / 4);
      const size_t sb = (size_t)node * (D / 4);
      #pragma unroll
      for (int it = 0; it < 17; ++it) {
        int idx = lane + it * 64;
        if (idx < 1056) {  // only it==16 partially masked (lanes 0..31: self row)
          float4 v = (idx < 1024) ? neigh4[nb + idx] : self4[sb + (idx - 1024)];
          int row = idx >> 5, c4 = idx & 31;
          bf16x4 b = { (bf16)v.x, (bf16)v.y, (bf16)v.z, (bf16)v.w };
          *(bf16x4*)&Xw[row * LDP + (c4 << 2)] = b;
        }
      }
    }
    __threadfence_block();  // drain lgkm: wave-local LDS writes visible to wave's reads

    // ---- H[48][128] = X @ W ; rows 33..47 are garbage (outputs ignored) ----
    f32x4 acc[3][8];
    #pragma unroll
    for (int mt = 0; mt < 3; ++mt)
      #pragma unroll
      for (int nt = 0; nt < 8; ++nt)
        acc[mt][nt] = (f32x4){0.f, 0.f, 0.f, 0.f};

    #pragma unroll
    for (int ks = 0; ks < 4; ++ks) {
      bf16x8 A[3], B[8];
      #pragma unroll
      for (int mt = 0; mt < 3; ++mt)   // A[m=l15][k=q*8+j]
        A[mt] = *(const bf16x8*)&Xw[(mt * 16 + l15) * LDP + ks * 32 + q * 8];
      #pragma unroll
      for (int nt = 0; nt < 8; ++nt)   // B[k=q*8+j][n=l15]
        B[nt] = *(const bf16x8*)&Wt[nt * 16 + l15][ks * 32 + q * 8];
      #pragma unroll
      for (int mt = 0; mt < 3; ++mt)
        #pragma unroll
        for (int nt = 0; nt < 8; ++nt)
          acc[mt][nt] = __builtin_amdgcn_mfma_f32_16x16x32_bf16(A[mt], B[nt], acc[mt][nt], 0, 0, 0);
    }

    // ---- logits: logit[row] = H[row][:] . attn ; C/D layout col=l15, row=q*4+r ----
    // butterfly over l15 leaves each row's logit replicated across its 16-lane q-group
    float lg[2][4];
    #pragma unroll
    for (int mt = 0; mt < 2; ++mt)
      #pragma unroll
      for (int r = 0; r < 4; ++r) {
        float v = 0.f;
        #pragma unroll
        for (int nt = 0; nt < 8; ++nt) v += acc[mt][nt][r] * av[nt];
        v += __shfl_xor(v, 1); v += __shfl_xor(v, 2);
        v += __shfl_xor(v, 4); v += __shfl_xor(v, 8);
        lg[mt][r] = v;  // logit for row mt*16 + q*4 + r
      }
    float sl;
    {
      float v = 0.f;  // self logit: row 32 = (mt=2, q=0, r=0)
      #pragma unroll
      for (int nt = 0; nt < 8; ++nt) v += acc[2][nt][0] * av[nt];
      v += __shfl_xor(v, 1); v += __shfl_xor(v, 2);
      v += __shfl_xor(v, 4); v += __shfl_xor(v, 8);
      sl = __shfl(v, l15);  // broadcast from q=0 group (lane l15) to all
    }

    // ---- leaky_relu + softmax over the 32 neighbor rows (all in-register) ----
    float e[2][4];
    float mx = -3.4e38f;
    #pragma unroll
    for (int mt = 0; mt < 2; ++mt)
      #pragma unroll
      for (int r = 0; r < 4; ++r) {
        float t = lg[mt][r] + sl;
        t = t > 0.f ? t : 0.2f * t;
        e[mt][r] = t;
        mx = fmaxf(mx, t);
      }
    mx = fmaxf(mx, __shfl_xor(mx, 16));
    mx = fmaxf(mx, __shfl_xor(mx, 32));   // max over all 32 rows, every lane
    float s = 0.f;
    #pragma unroll
    for (int mt = 0; mt < 2; ++mt)
      #pragma unroll
      for (int r = 0; r < 4; ++r) {
        e[mt][r] = __expf(e[mt][r] - mx);
        s += e[mt][r];
      }
    s += __shfl_xor(s, 16);
    s += __shfl_xor(s, 32);
    const float inv = 1.0f / s;

    // ---- aggregation + epilogue: out[c] = relu(h_self[c] + sum_row coef*H[row][c] + bias[c]) ----
    #pragma unroll
    for (int nt = 0; nt < 8; ++nt) {
      float p = 0.f;
      #pragma unroll
      for (int mt = 0; mt < 2; ++mt)
        #pragma unroll
        for (int r = 0; r < 4; ++r)
          p += e[mt][r] * acc[mt][nt][r];   // rows q*4+r, 16+q*4+r (this lane's)
      p *= inv;
      p += __shfl_xor(p, 16);
      p += __shfl_xor(p, 32);               // sum the 4 q-groups -> all 32 rows
      float hs = __shfl(acc[2][nt][0], l15); // h_self[col] from q=0 group
      float ov = fmaxf(hs + p + bv[nt], 0.f);
      if (q == (nt >> 1))                    // 2 stores per lane, cols nt*16+l15
        out[(size_t)node * D + nt * 16 + l15] = ov;
    }
  }
}

extern "C" void kernel_launch(void* const* d_in, const int* in_sizes, int n_in,
                              void* d_out, int out_size, void* d_ws, size_t ws_size,
                              hipStream_t stream) {
  const float* selfv  = (const float*)d_in[0];
  const float* neighv = (const float*)d_in[1];
  const float* W      = (const float*)d_in[2];
  const float* attn   = (const float*)d_in[3];
  const float* biasp  = (const float*)d_in[4];
  float* out = (float*)d_out;
  const int nnodes = in_sizes[0] / D;

  const int use_ws = (ws_size >= (size_t)(D * D * sizeof(bf16))) ? 1 : 0;
  bf16* Wt_g = (bf16*)d_ws;
  if (use_ws)
    prep_wt_kernel<<<(D * D + 255) / 256, 256, 0, stream>>>(W, Wt_g);

  const int nwaves  = (nnodes + NPW - 1) / NPW;
  const int nblocks = (nwaves + 3) / 4;
  gat_kernel<<<nblocks, 256, 0, stream>>>(selfv, neighv, W, Wt_g, attn, biasp,
                                          out, nnodes, use_ws);
}